// Round 1
// baseline (2615.523 us; speedup 1.0000x reference)
//
#include <hip/hip_runtime.h>

#define NACT 200000
#define KOFF 27
#define BM 192               // out-rows per tile
#define NT 1042              // ceil(NACT/BM); NT*BM = 200064, last tile = 128 rows
#define NSEG (NT + 1)
#define ACCW 65              // odd stride -> LDS bank spread for scatter
#define DUMP 192             // dump row for pad lanes (adds exact 0.f)
#define NBLK2 (NT * 2)       // spconv grid (tile x col-half)

typedef __bf16 bf16x8 __attribute__((ext_vector_type(8)));
typedef __bf16 bf16x4 __attribute__((ext_vector_type(4)));
typedef float f32x4 __attribute__((ext_vector_type(4)));

// ---------------- rulebook segmentation ----------------
// out_idx[k] is sorted ascending, pads (=NACT) at the end -> whole row sorted.
// seg[k][t] = lower_bound(out_idx[k], min(t*BM, NACT)); valid pairs for
// (offset k, tile t) are [seg[k][t], seg[k][t+1]).
__global__ void seg_search(const int* __restrict__ oi, int* __restrict__ seg) {
  int id = blockIdx.x * 256 + threadIdx.x;
  if (id >= KOFF * NSEG) return;
  int k = id / NSEG, t = id - k * NSEG;
  int target = t * BM; if (target > NACT) target = NACT;
  const int* a = oi + (size_t)k * NACT;
  int lo = 0, hi = NACT;
  while (lo < hi) { int mid = (lo + hi) >> 1; if (a[mid] < target) lo = mid + 1; else hi = mid; }
  seg[id] = lo;
}

// ---------------- casts / transposes ----------------
__global__ void cast_feats(const float* __restrict__ F, __bf16* __restrict__ X) {
  int i = blockIdx.x * 256 + threadIdx.x;        // float4 groups, (NACT+1)*32
  if (i >= (NACT + 1) * 32) return;
  float4 v = (i < NACT * 32) ? ((const float4*)F)[i] : make_float4(0.f, 0.f, 0.f, 0.f);
  bf16x4 o = {(__bf16)v.x, (__bf16)v.y, (__bf16)v.z, (__bf16)v.w};
  *(bf16x4*)(X + (i << 2)) = o;
}

__global__ void prep_w(const float* __restrict__ W1, const float* __restrict__ W2,
                       __bf16* __restrict__ T1, __bf16* __restrict__ T2) {
  int i = blockIdx.x * 256 + threadIdx.x;        // WT[k][n][c] = W[k][c][n]
  if (i >= KOFF * 128 * 128) return;
  int k = i >> 14, rem = i & 16383, n = rem >> 7, c = rem & 127;
  int src = (k << 14) + (c << 7) + n;
  T1[i] = (__bf16)W1[src];
  T2[i] = (__bf16)W2[src];
}

// ---------------- sparse rulebook gather-GEMM with LDS f32 scatter-acc ----------------
// block = (tile of BM out-rows) x (64-col half). Only valid rulebook pairs are
// processed, in chunks of 16 gathered rows. B half-panel (64x128) lives in 64
// VGPRs per wave, reloaded on offset change. Scatter-add via ds_add_f32 (LDS
// atomics) -> no barriers in the hot loop, cross-wave accumulation race-free.
__global__ __launch_bounds__(256, 3) void spconv(
    const __bf16* __restrict__ X,    // [NACT+1][128], row NACT = 0
    const __bf16* __restrict__ WT,   // [27][128][128] : WT[k][n][c]
    const int* __restrict__ seg,     // [27][NSEG]
    const int* __restrict__ ii,      // [27][NACT] in rows
    const int* __restrict__ oi,      // [27][NACT] out rows (sorted per k)
    __bf16* __restrict__ Y,          // [NACT][128]
    float* __restrict__ Pst)         // [NBLK2][256] : b*256 + kind*128 + col
{
  __shared__ float acc[(BM + 1) * ACCW];   // 193*65*4 = 50180 B
  __shared__ float red[512];
  __shared__ int sS[KOFF], sE[KOFF], nchs[KOFF], csum[KOFF + 1];

  const int t = threadIdx.x;
  const int lane = t & 63;
  const int w = t >> 6;
  const int l15 = lane & 15;
  const int q4 = lane >> 4;
  const int tile = blockIdx.x >> 1;
  const int h = blockIdx.x & 1;
  const int m0 = tile * BM;
  const int rows = (NACT - m0 < BM) ? (NACT - m0) : BM;

  for (int i = t; i < (BM + 1) * ACCW; i += 256) acc[i] = 0.f;
  if (t < KOFF) {
    int s = seg[t * NSEG + tile], e = seg[t * NSEG + tile + 1];
    sS[t] = s; sE[t] = e; nchs[t] = (e - s + 15) >> 4;
  }
  __syncthreads();
  if (t == 0) {
    int c = 0;
    for (int k = 0; k < KOFF; ++k) { csum[k] = c; c += nchs[k]; }
    csum[KOFF] = c;
  }
  __syncthreads();

  const int total = csum[KOFF];
  const int per = (total + 3) >> 2;            // contiguous chunk range per wave
  int g = w * per;
  int gend = g + per; if (gend > total) gend = total;

  int kc = 0, kprev = -1;
  int iiv = NACT, oiv = DUMP;
  if (g < gend) {
    while (csum[kc + 1] <= g) ++kc;
    if (lane < 16) {
      int p = sS[kc] + ((g - csum[kc]) << 4) + lane;
      if (p < sE[kc]) { iiv = ii[kc * NACT + p]; oiv = oi[kc * NACT + p] - m0; }
    }
  }

  bf16x8 bf[4][4];
  while (g < gend) {
    if (kc != kprev) {                          // reload B half-panel into regs
      const __bf16* wb = WT + (kc << 14) + (h << 13);
#pragma unroll
      for (int ni = 0; ni < 4; ++ni)
#pragma unroll
        for (int ks = 0; ks < 4; ++ks)
          bf[ni][ks] = *(const bf16x8*)(wb + (((ni << 4) + l15) << 7) + ks * 32 + (q4 << 3));
      kprev = kc;
    }
    const int rowA = __shfl(iiv, l15);
    const int or0 = __shfl(oiv, (q4 << 2) + 0);
    const int or1 = __shfl(oiv, (q4 << 2) + 1);
    const int or2 = __shfl(oiv, (q4 << 2) + 2);
    const int or3 = __shfl(oiv, (q4 << 2) + 3);
    const __bf16* xr = X + ((size_t)rowA << 7) + (q4 << 3);
    bf16x8 af0 = *(const bf16x8*)(xr);
    bf16x8 af1 = *(const bf16x8*)(xr + 32);
    bf16x8 af2 = *(const bf16x8*)(xr + 64);
    bf16x8 af3 = *(const bf16x8*)(xr + 96);

    // prefetch next chunk's indices (hide idx->shfl->gather chain)
    int gn = g + 1, kn = kc;
    int iin = NACT, oin = DUMP;
    if (gn < gend) {
      while (csum[kn + 1] <= gn) ++kn;
      if (lane < 16) {
        int p = sS[kn] + ((gn - csum[kn]) << 4) + lane;
        if (p < sE[kn]) { iin = ii[kn * NACT + p]; oin = oi[kn * NACT + p] - m0; }
      }
    }

#pragma unroll
    for (int ni = 0; ni < 4; ++ni) {
      f32x4 cf = {0.f, 0.f, 0.f, 0.f};
      cf = __builtin_amdgcn_mfma_f32_16x16x32_bf16(af0, bf[ni][0], cf, 0, 0, 0);
      cf = __builtin_amdgcn_mfma_f32_16x16x32_bf16(af1, bf[ni][1], cf, 0, 0, 0);
      cf = __builtin_amdgcn_mfma_f32_16x16x32_bf16(af2, bf[ni][2], cf, 0, 0, 0);
      cf = __builtin_amdgcn_mfma_f32_16x16x32_bf16(af3, bf[ni][3], cf, 0, 0, 0);
      const int cb = (ni << 4) + l15;
      atomicAdd(&acc[or0 * ACCW + cb], cf[0]);
      atomicAdd(&acc[or1 * ACCW + cb], cf[1]);
      atomicAdd(&acc[or2 * ACCW + cb], cf[2]);
      atomicAdd(&acc[or3 * ACCW + cb], cf[3]);
    }
    g = gn; kc = kn; iiv = iin; oiv = oin;
  }
  __syncthreads();

  // ---- epilogue: bf16 Y write + BN stat partials from LDS acc ----
  float s1 = 0.f, s2 = 0.f;
  const int col = t & 63;
  const int rq = t >> 6;
  for (int r = rq; r < rows; r += 4) {
    float v = acc[r * ACCW + col];
    s1 += v; s2 += v * v;
    Y[((size_t)(m0 + r) << 7) + (h << 6) + col] = (__bf16)v;
  }
  red[t] = s1; red[256 + t] = s2;
  __syncthreads();
  if (t < 128) {
    const int kind = t >> 6, c = t & 63;
    const float* rp = red + (kind << 8);
    float v = rp[c] + rp[64 + c] + rp[128 + c] + rp[192 + c];
    float* pb = Pst + ((size_t)blockIdx.x << 8);
    pb[(kind << 7) + (h << 6) + c] = v;
    pb[(kind << 7) + ((1 - h) << 6) + c] = 0.f;   // other col-half: zero so reduce is total
  }
}

// ---------------- fused stats reduce + BN coeffs (single block) ----------------
__global__ void stats_coeffs(const float* __restrict__ Pst, const float* __restrict__ gamma,
                             const float* __restrict__ beta, float* __restrict__ co) {
  __shared__ float part[4][256];
  int t = threadIdx.x;                  // 1024
  int p = t & 255, q = t >> 8;
  int per = (NBLK2 + 3) >> 2;
  int b0 = q * per, b1 = b0 + per; if (b1 > NBLK2) b1 = NBLK2;
  float s = 0.f;
  for (int b = b0; b < b1; ++b) s += Pst[((size_t)b << 8) + p];
  part[q][p] = s;
  __syncthreads();
  if (t < 256) part[0][t] = part[0][t] + part[1][t] + part[2][t] + part[3][t];
  __syncthreads();
  if (t < 128) {
    float m = part[0][t] * (1.f / NACT);
    float v = part[0][128 + t] * (1.f / NACT) - m * m;
    float sc = gamma[t] * rsqrtf(v + 1e-4f);
    co[t] = sc;
    co[128 + t] = beta[t] - m * sc;
  }
}

// ---------------- fused elementwise ----------------
__global__ void bn_relu_cast(const __bf16* __restrict__ Y, const float* __restrict__ co,
                             __bf16* __restrict__ X2) {
  int i = blockIdx.x * 256 + threadIdx.x;   // 8-elem chunks, (NACT+1)*16
  if (i >= (NACT + 1) * 16) return;
  bf16x8 o;
  if (i < NACT * 16) {
    bf16x8 v = ((const bf16x8*)Y)[i];
    int cg = (i & 15) << 3;
#pragma unroll
    for (int e = 0; e < 8; ++e) {
      float x = fmaf((float)v[e], co[cg + e], co[128 + cg + e]);
      o[e] = (__bf16)fmaxf(x, 0.f);
    }
  } else {
#pragma unroll
    for (int e = 0; e < 8; ++e) o[e] = (__bf16)0.f;
  }
  ((bf16x8*)X2)[i] = o;
}

__global__ void bn_add_relu(const __bf16* __restrict__ Y, const float* __restrict__ co,
                            const float* __restrict__ F, float* __restrict__ O) {
  int i = blockIdx.x * 256 + threadIdx.x;   // 8-elem chunks, NACT*16
  if (i >= NACT * 16) return;
  bf16x8 v = ((const bf16x8*)Y)[i];
  float4 f0 = ((const float4*)F)[2 * i];
  float4 f1 = ((const float4*)F)[2 * i + 1];
  int cg = (i & 15) << 3;
  float4 o0, o1;
  o0.x = fmaxf(fmaf((float)v[0], co[cg + 0], co[128 + cg + 0]) + f0.x, 0.f);
  o0.y = fmaxf(fmaf((float)v[1], co[cg + 1], co[128 + cg + 1]) + f0.y, 0.f);
  o0.z = fmaxf(fmaf((float)v[2], co[cg + 2], co[128 + cg + 2]) + f0.z, 0.f);
  o0.w = fmaxf(fmaf((float)v[3], co[cg + 3], co[128 + cg + 3]) + f0.w, 0.f);
  o1.x = fmaxf(fmaf((float)v[4], co[cg + 4], co[128 + cg + 4]) + f1.x, 0.f);
  o1.y = fmaxf(fmaf((float)v[5], co[cg + 5], co[128 + cg + 5]) + f1.y, 0.f);
  o1.z = fmaxf(fmaf((float)v[6], co[cg + 6], co[128 + cg + 6]) + f1.z, 0.f);
  o1.w = fmaxf(fmaf((float)v[7], co[cg + 7], co[128 + cg + 7]) + f1.w, 0.f);
  ((float4*)O)[2 * i] = o0;
  ((float4*)O)[2 * i + 1] = o1;
}

// ---------------- launcher ----------------
extern "C" void kernel_launch(void* const* d_in, const int* in_sizes, int n_in,
                              void* d_out, int out_size, void* d_ws, size_t ws_size,
                              hipStream_t stream) {
  const float* features = (const float*)d_in[0];
  const float* W1       = (const float*)d_in[1];
  const float* gamma1   = (const float*)d_in[2];
  const float* beta1    = (const float*)d_in[3];
  const float* W2       = (const float*)d_in[4];
  const float* gamma2   = (const float*)d_in[5];
  const float* beta2    = (const float*)d_in[6];
  const int* in_idx     = (const int*)d_in[7];   // int32 (JAX x64 disabled)
  const int* out_idx    = (const int*)d_in[8];

  char* ws = (char*)d_ws;
  size_t off = 0;
  int*    seg = (int*)(ws + off);    off += ((size_t)KOFF * NSEG * 4 + 255) & ~255ull;  // 112.7 KB
  __bf16* X   = (__bf16*)(ws + off); off += (size_t)(NACT + 1) * 128 * 2;               // 51.2 MB (X1 -> X2)
  __bf16* T1  = (__bf16*)(ws + off); off += (size_t)KOFF * 128 * 128 * 2;               // 0.88 MB
  __bf16* T2  = (__bf16*)(ws + off); off += (size_t)KOFF * 128 * 128 * 2;               // 0.88 MB
  __bf16* Y   = (__bf16*)(ws + off); off += (size_t)NACT * 128 * 2;                     // 51.2 MB
  float*  Pst = (float*)(ws + off);  off += (size_t)NBLK2 * 256 * 4;                    // 2.13 MB
  float*  st  = (float*)(ws + off);  off += 4096;   // co1 at st, co2 at st+256 floats

  seg_search<<<(KOFF * NSEG + 255) / 256, 256, 0, stream>>>(out_idx, seg);
  cast_feats<<<((NACT + 1) * 32 + 255) / 256, 256, 0, stream>>>(features, X);
  prep_w<<<(KOFF * 128 * 128 + 255) / 256, 256, 0, stream>>>(W1, W2, T1, T2);

  spconv<<<NBLK2, 256, 0, stream>>>(X, T1, seg, in_idx, out_idx, Y, Pst);
  stats_coeffs<<<1, 1024, 0, stream>>>(Pst, gamma1, beta1, st);
  bn_relu_cast<<<((NACT + 1) * 16 + 255) / 256, 256, 0, stream>>>(Y, st, X);

  spconv<<<NBLK2, 256, 0, stream>>>(X, T2, seg, in_idx, out_idx, Y, Pst);
  stats_coeffs<<<1, 1024, 0, stream>>>(Pst, gamma2, beta2, st + 256);
  bn_add_relu<<<(NACT * 16 + 255) / 256, 256, 0, stream>>>(Y, st + 256, features, (float*)d_out);
}

// Round 2
// 691.425 us; speedup vs baseline: 3.7828x; 3.7828x over previous
//
#include <hip/hip_runtime.h>

#define NACT 200000
#define MPAD 200064          // ceil(NACT/128)*128
#define NBLK 1563            // MPAD/128
#define KOFF 27
#define NSTAGE (KOFF * 2)    // 54 stages of 64 K-columns

typedef __bf16 bf16x8 __attribute__((ext_vector_type(8)));
typedef __bf16 bf16x4 __attribute__((ext_vector_type(4)));
typedef float f32x4 __attribute__((ext_vector_type(4)));

__device__ __forceinline__ void async_load16(const void* g, void* l) {
  __builtin_amdgcn_global_load_lds(
      (__attribute__((address_space(1))) void*)g,
      (__attribute__((address_space(3))) void*)l, 16, 0, 0);
}

// ---------------- rulebook inversion ----------------
__global__ void fill_g(int* __restrict__ G) {
  int i = blockIdx.x * 256 + threadIdx.x;
  if (i < KOFF * MPAD) G[i] = NACT;   // dummy row (zero features)
}

__global__ void scatter_g(const int* __restrict__ ii, const int* __restrict__ oi,
                          int* __restrict__ G) {
  int i = blockIdx.x * 256 + threadIdx.x;
  if (i >= KOFF * NACT) return;
  int k = i / NACT;
  int o = oi[i];                  // pad entries: o == NACT -> row NACT (fixed below)
  G[k * MPAD + o] = ii[i];
}

// row NACT of G got polluted by pad entries; reset so Y row NACT is exactly 0
// (epilogue stats include padding rows and rely on them being zero).
__global__ void fix_g(int* __restrict__ G) {
  int k = threadIdx.x;
  if (k < KOFF) G[k * MPAD + NACT] = NACT;
}

// ---------------- casts / transposes ----------------
__global__ void cast_feats(const float* __restrict__ F, __bf16* __restrict__ X) {
  int i = blockIdx.x * 256 + threadIdx.x;        // float4 groups, (NACT+1)*32
  if (i >= (NACT + 1) * 32) return;
  float4 v = (i < NACT * 32) ? ((const float4*)F)[i] : make_float4(0.f, 0.f, 0.f, 0.f);
  bf16x4 o = {(__bf16)v.x, (__bf16)v.y, (__bf16)v.z, (__bf16)v.w};
  *(bf16x4*)(X + (i << 2)) = o;
}

__global__ void prep_w(const float* __restrict__ W1, const float* __restrict__ W2,
                       __bf16* __restrict__ T1, __bf16* __restrict__ T2) {
  int i = blockIdx.x * 256 + threadIdx.x;        // WT[k][n][c] = W[k][c][n]
  if (i >= KOFF * 128 * 128) return;
  int k = i >> 14, rem = i & 16383, n = rem >> 7, c = rem & 127;
  int src = (k << 14) + (c << 7) + n;
  T1[i] = (__bf16)W1[src];
  T2[i] = (__bf16)W2[src];
}

// ---------------- gather-GEMM: Y[m,:] = sum_k X[G[k][m],:] @ W[k] ----------------
// 128x128 tile per block, 4 waves (2x2 of 64x64), BK=64, XOR-8 LDS swizzle.
// T3/T4: double-buffered stage LDS, issue stage s+1 before computing stage s,
// counted s_waitcnt vmcnt(8) (never drain to 0 in the loop). G slice staged in
// LDS up-front so staging-load addresses have no global-load dependency.
// Epilogue: bf16 Y stores + per-block column sum/sumsq partials (BN stats fused).
__global__ __launch_bounds__(256, 2) void gemm_gather(
    const __bf16* __restrict__ X,   // [NACT+1][128], row NACT = 0
    const __bf16* __restrict__ WT,  // [27][128][128] : WT[k][n][c]
    const int* __restrict__ G,      // [27][MPAD]
    __bf16* __restrict__ Y,         // [MPAD][128] bf16
    float* __restrict__ Pst)        // [256][NBLK]: (kind*128+col)*NBLK + block
{
  __shared__ __bf16 Al0[128 * 64];
  __shared__ __bf16 Bl0[128 * 64];
  __shared__ __bf16 Al1[128 * 64];
  __shared__ __bf16 Bl1[128 * 64];
  __shared__ int Gl[KOFF * 128];     // 13.8 KB
  __shared__ float red[512];
  const int t = threadIdx.x;
  const int lane = t & 63;
  const int w = t >> 6;
  const int wm = (w & 1) << 6;
  const int wn = (w >> 1) << 6;
  const int m_base = blockIdx.x << 7;
  const int r0 = t >> 3;   // staging row group 0..31
  const int scb = t & 7;   // lds 16B-chunk slot within row
  const int l15 = lane & 15;
  const int q4 = lane >> 4;

  f32x4 acc[4][4];
#pragma unroll
  for (int i = 0; i < 4; ++i)
#pragma unroll
    for (int j = 0; j < 4; ++j) acc[i][j] = (f32x4){0.f, 0.f, 0.f, 0.f};

  // stage the block's G slice: Gl[k][r] = G[k][m_base + r]
  for (int i = t; i < KOFF * 128; i += 256)
    Gl[i] = G[(size_t)(i >> 7) * MPAD + m_base + (i & 127)];
  __syncthreads();

  // issue 8 global_load_lds for stage sidx into buffers AL/BL.
  // LDS dest is linear in t (wave-uniform base + lane*16) as global_load_lds
  // requires; the XOR-8 swizzle is applied on the GLOBAL source side (gcb).
#define STAGE_ISSUE(sidx, AL, BL)                                              \
  do {                                                                         \
    const int k_ = (sidx) >> 1;                                                \
    const int c0_ = ((sidx) & 1) << 6;                                         \
    const __bf16* wb_ = WT + (k_ << 14);                                       \
    _Pragma("unroll") for (int j = 0; j < 4; ++j) {                            \
      const int r_ = r0 + j * 32;                                              \
      const int rowA_ = Gl[(k_ << 7) + r_];                                    \
      const int gcb_ = scb ^ (r_ & 7);                                         \
      async_load16(wb_ + (r_ << 7) + c0_ + (gcb_ << 3),                        \
                   &(BL)[(((r_ << 3) + scb) << 3)]);                           \
      async_load16(X + ((size_t)rowA_ << 7) + c0_ + (gcb_ << 3),               \
                   &(AL)[(((r_ << 3) + scb) << 3)]);                           \
    }                                                                          \
  } while (0)

#define STAGE_COMPUTE(AL, BL)                                                  \
  do {                                                                         \
    _Pragma("unroll") for (int ks = 0; ks < 2; ++ks) {                         \
      bf16x8 af[4], bfr[4];                                                    \
      const int cb0 = (ks << 2) + q4;                                          \
      _Pragma("unroll") for (int mi = 0; mi < 4; ++mi) {                       \
        const int r = wm + mi * 16 + l15;                                      \
        af[mi] = *(const bf16x8*)&(AL)[(((r << 3) + (cb0 ^ (r & 7))) << 3)];   \
      }                                                                        \
      _Pragma("unroll") for (int ni = 0; ni < 4; ++ni) {                       \
        const int r = wn + ni * 16 + l15;                                      \
        bfr[ni] = *(const bf16x8*)&(BL)[(((r << 3) + (cb0 ^ (r & 7))) << 3)];  \
      }                                                                        \
      _Pragma("unroll") for (int mi = 0; mi < 4; ++mi)                         \
          _Pragma("unroll") for (int ni = 0; ni < 4; ++ni)                     \
              acc[mi][ni] = __builtin_amdgcn_mfma_f32_16x16x32_bf16(           \
                  af[mi], bfr[ni], acc[mi][ni], 0, 0, 0);                      \
    }                                                                          \
  } while (0)

  STAGE_ISSUE(0, Al0, Bl0);
  for (int s = 0; s < NSTAGE; s += 2) {
    // even stage s -> buf0
    if (s + 1 < NSTAGE) STAGE_ISSUE(s + 1, Al1, Bl1);
    asm volatile("s_waitcnt vmcnt(8)" ::: "memory");   // stage-s loads landed
    __builtin_amdgcn_s_barrier();                      // ...for ALL waves
    __builtin_amdgcn_sched_barrier(0);
    STAGE_COMPUTE(Al0, Bl0);
    __builtin_amdgcn_sched_barrier(0);
    __builtin_amdgcn_s_barrier();                      // buf0 consumed everywhere
    // odd stage s+1 -> buf1
    if (s + 2 < NSTAGE) {
      STAGE_ISSUE(s + 2, Al0, Bl0);
      asm volatile("s_waitcnt vmcnt(8)" ::: "memory");
    } else {
      asm volatile("s_waitcnt vmcnt(0)" ::: "memory");
    }
    __builtin_amdgcn_s_barrier();
    __builtin_amdgcn_sched_barrier(0);
    STAGE_COMPUTE(Al1, Bl1);
    __builtin_amdgcn_sched_barrier(0);
    __builtin_amdgcn_s_barrier();
  }
#undef STAGE_ISSUE
#undef STAGE_COMPUTE

  // ---- epilogue 1: bf16 Y stores (C/D layout: col=lane&15, row=quad*4+reg) ----
#pragma unroll
  for (int mi = 0; mi < 4; ++mi) {
#pragma unroll
    for (int ni = 0; ni < 4; ++ni) {
      const int col = wn + ni * 16 + l15;
#pragma unroll
      for (int rg = 0; rg < 4; ++rg) {
        const int row = m_base + wm + mi * 16 + (q4 << 2) + rg;
        Y[(row << 7) + col] = (__bf16)acc[mi][ni][rg];
      }
    }
  }

  // ---- epilogue 2: BN stats partials (padding rows are zero -> harmless) ----
  float s[4], s2[4];
#pragma unroll
  for (int ni = 0; ni < 4; ++ni) {
    float a = 0.f, b = 0.f;
#pragma unroll
    for (int mi = 0; mi < 4; ++mi)
#pragma unroll
      for (int rg = 0; rg < 4; ++rg) {
        float v = acc[mi][ni][rg];
        a += v; b += v * v;
      }
    s[ni] = a; s2[ni] = b;
  }
#pragma unroll
  for (int ni = 0; ni < 4; ++ni) {
    s[ni]  += __shfl_xor(s[ni], 16);  s[ni]  += __shfl_xor(s[ni], 32);
    s2[ni] += __shfl_xor(s2[ni], 16); s2[ni] += __shfl_xor(s2[ni], 32);
  }
  __syncthreads();
  if (q4 == 0) {
#pragma unroll
    for (int ni = 0; ni < 4; ++ni) {
      red[(w << 6) + ni * 16 + l15]       = s[ni];
      red[256 + (w << 6) + ni * 16 + l15] = s2[ni];
    }
  }
  __syncthreads();
  // t in [0,256): kind=t>>7, col=t&127; combine the two row-half waves
  {
    const int kind = t >> 7, col = t & 127;
    const int w1 = (col >> 6) << 1;
    const float v = red[kind * 256 + (w1 << 6) + (col & 63)] +
                    red[kind * 256 + ((w1 + 1) << 6) + (col & 63)];
    Pst[(size_t)t * NBLK + blockIdx.x] = v;
  }
}

// ---------------- fused stats tree-reduce + BN coeffs ----------------
// grid 128: block c reduces sum (row c) and sumsq (row 128+c) over NBLK partials
__global__ void stats_coeffs(const float* __restrict__ P, const float* __restrict__ gamma,
                             const float* __restrict__ beta, float* __restrict__ co) {
  int c = blockIdx.x;
  const float* p1 = P + (size_t)c * NBLK;
  const float* p2 = P + (size_t)(128 + c) * NBLK;
  float s = 0.f, s2 = 0.f;
  for (int i = threadIdx.x; i < NBLK; i += 256) { s += p1[i]; s2 += p2[i]; }
  for (int off = 32; off; off >>= 1) { s += __shfl_down(s, off); s2 += __shfl_down(s2, off); }
  __shared__ float ls[8];
  if ((threadIdx.x & 63) == 0) { ls[threadIdx.x >> 6] = s; ls[4 + (threadIdx.x >> 6)] = s2; }
  __syncthreads();
  if (threadIdx.x == 0) {
    float S = ls[0] + ls[1] + ls[2] + ls[3];
    float S2 = ls[4] + ls[5] + ls[6] + ls[7];
    float m = S * (1.f / NACT);
    float v = S2 * (1.f / NACT) - m * m;
    float sc = gamma[c] * rsqrtf(v + 1e-4f);
    co[c] = sc;
    co[128 + c] = beta[c] - m * sc;
  }
}

// ---------------- fused elementwise ----------------
__global__ void bn_relu_cast(const __bf16* __restrict__ Y, const float* __restrict__ co,
                             __bf16* __restrict__ X2) {
  int i = blockIdx.x * 256 + threadIdx.x;   // 8-elem chunks, (NACT+1)*16
  if (i >= (NACT + 1) * 16) return;
  bf16x8 o;
  if (i < NACT * 16) {
    bf16x8 v = ((const bf16x8*)Y)[i];
    int cg = (i & 15) << 3;
#pragma unroll
    for (int e = 0; e < 8; ++e) {
      float x = fmaf((float)v[e], co[cg + e], co[128 + cg + e]);
      o[e] = (__bf16)fmaxf(x, 0.f);
    }
  } else {
#pragma unroll
    for (int e = 0; e < 8; ++e) o[e] = (__bf16)0.f;
  }
  ((bf16x8*)X2)[i] = o;
}

__global__ void bn_add_relu(const __bf16* __restrict__ Y, const float* __restrict__ co,
                            const float* __restrict__ F, float* __restrict__ O) {
  int i = blockIdx.x * 256 + threadIdx.x;   // 8-elem chunks, NACT*16
  if (i >= NACT * 16) return;
  bf16x8 v = ((const bf16x8*)Y)[i];
  float4 f0 = ((const float4*)F)[2 * i];
  float4 f1 = ((const float4*)F)[2 * i + 1];
  int cg = (i & 15) << 3;
  float4 o0, o1;
  o0.x = fmaxf(fmaf((float)v[0], co[cg + 0], co[128 + cg + 0]) + f0.x, 0.f);
  o0.y = fmaxf(fmaf((float)v[1], co[cg + 1], co[128 + cg + 1]) + f0.y, 0.f);
  o0.z = fmaxf(fmaf((float)v[2], co[cg + 2], co[128 + cg + 2]) + f0.z, 0.f);
  o0.w = fmaxf(fmaf((float)v[3], co[cg + 3], co[128 + cg + 3]) + f0.w, 0.f);
  o1.x = fmaxf(fmaf((float)v[4], co[cg + 4], co[128 + cg + 4]) + f1.x, 0.f);
  o1.y = fmaxf(fmaf((float)v[5], co[cg + 5], co[128 + cg + 5]) + f1.y, 0.f);
  o1.z = fmaxf(fmaf((float)v[6], co[cg + 6], co[128 + cg + 6]) + f1.z, 0.f);
  o1.w = fmaxf(fmaf((float)v[7], co[cg + 7], co[128 + cg + 7]) + f1.w, 0.f);
  ((float4*)O)[2 * i] = o0;
  ((float4*)O)[2 * i + 1] = o1;
}

// ---------------- launcher ----------------
extern "C" void kernel_launch(void* const* d_in, const int* in_sizes, int n_in,
                              void* d_out, int out_size, void* d_ws, size_t ws_size,
                              hipStream_t stream) {
  const float* features = (const float*)d_in[0];
  const float* W1       = (const float*)d_in[1];
  const float* gamma1   = (const float*)d_in[2];
  const float* beta1    = (const float*)d_in[3];
  const float* W2       = (const float*)d_in[4];
  const float* gamma2   = (const float*)d_in[5];
  const float* beta2    = (const float*)d_in[6];
  const int* in_idx     = (const int*)d_in[7];
  const int* out_idx    = (const int*)d_in[8];

  char* ws = (char*)d_ws;
  size_t off = 0;
  int*    G   = (int*)(ws + off);    off += (size_t)KOFF * MPAD * 4;          // 21.6 MB
  __bf16* X   = (__bf16*)(ws + off); off += (size_t)(NACT + 1) * 128 * 2;     // 51.2 MB (X1, reused as X2)
  __bf16* T1  = (__bf16*)(ws + off); off += (size_t)KOFF * 128 * 128 * 2;     // 0.88 MB
  __bf16* T2  = (__bf16*)(ws + off); off += (size_t)KOFF * 128 * 128 * 2;     // 0.88 MB
  __bf16* Y   = (__bf16*)(ws + off); off += (size_t)MPAD * 128 * 2;           // 51.2 MB (Y1, reused as Y2)
  float*  Pst = (float*)(ws + off);  off += (size_t)256 * NBLK * 4;           // 1.6 MB
  float*  st  = (float*)(ws + off);  off += 4096;
  // st: [0:256) coeffs1, [256:512) coeffs2 (as floats: st, st+128 | st+256, st+384)

  fill_g<<<(KOFF * MPAD + 255) / 256, 256, 0, stream>>>(G);
  scatter_g<<<(KOFF * NACT + 255) / 256, 256, 0, stream>>>(in_idx, out_idx, G);
  fix_g<<<1, 32, 0, stream>>>(G);
  cast_feats<<<((NACT + 1) * 32 + 255) / 256, 256, 0, stream>>>(features, X);
  prep_w<<<(KOFF * 128 * 128 + 255) / 256, 256, 0, stream>>>(W1, W2, T1, T2);

  gemm_gather<<<NBLK, 256, 0, stream>>>(X, T1, G, Y, Pst);
  stats_coeffs<<<128, 256, 0, stream>>>(Pst, gamma1, beta1, st);
  bn_relu_cast<<<((NACT + 1) * 16 + 255) / 256, 256, 0, stream>>>(Y, st, X);

  gemm_gather<<<NBLK, 256, 0, stream>>>(X, T2, G, Y, Pst);
  stats_coeffs<<<128, 256, 0, stream>>>(Pst, gamma2, beta2, st + 256);
  bn_add_relu<<<(NACT * 16 + 255) / 256, 256, 0, stream>>>(Y, st + 256, features, (float*)d_out);
}